// Round 2
// baseline (444.216 us; speedup 1.0000x reference)
//
#include <hip/hip_runtime.h>
#include <hip/hip_bf16.h>

// r4: 407us. r5: 357us; k_attn 127us (MfmaUtil 35, VALU 43, LDS-volume-bound),
//     others ~230us (k_qkv dominant, reg-staged).
// r6: k_attn: 64q/wave (2 groups share K/V frags) -> LDS+fetch per-work halved; grid (8,48).
//     k_qkv: global_load_lds staging, linear [128][32] tiles + 2-bit chunk-XOR swizzle.

typedef unsigned short u16;
typedef unsigned int   u32;
typedef __attribute__((ext_vector_type(4)))  float floatx4;
typedef __attribute__((ext_vector_type(16))) float floatx16;
typedef __attribute__((ext_vector_type(8)))  short shortx8;
typedef __attribute__((ext_vector_type(2)))  unsigned int uintx2;

#define EMB   768
#define SEQ   2048
#define NHEAD 12
#define HDIM  64
#define RPM   4096   // rows per modal (B*N)
#define NROW  8192   // total rows (2 modals)
#define NUNIT 48     // modal*B*H units
#define LDA   40     // padded LDS stride (bf16) for k_proj tiles (BK=32)
#define KTS   4096   // attn LDS tile elems (64*64)

__device__ __forceinline__ float bf2f(u16 h) {
  union { u32 u; float f; } v; v.u = ((u32)h) << 16; return v.f;
}
__device__ __forceinline__ u16 f2bf(float f) {            // RNE
  union { float f; u32 u; } v; v.f = f;
  u32 r = v.u + 0x7fffu + ((v.u >> 16) & 1u);
  return (u16)(r >> 16);
}
__device__ __forceinline__ u32 cvtpk_bf16(float a, float b) {  // lo16=bf16(a), hi16=bf16(b)
  u32 r;
  asm("v_cvt_pk_bf16_f32 %0, %1, %2" : "=v"(r) : "v"(a), "v"(b));
  return r;
}
// x = {a.lo32lanes, b.lo32lanes}, y = {a.hi32lanes, b.hi32lanes}
__device__ __forceinline__ void swap_halves(u32 a, u32 b, u32& x, u32& y) {
#if __has_builtin(__builtin_amdgcn_permlane32_swap)
  uintx2 r = __builtin_amdgcn_permlane32_swap(a, b, false, false);
  x = r.x; y = r.y;
#else
  u32 ax = (u32)__shfl_xor((int)a, 32);
  u32 bx = (u32)__shfl_xor((int)b, 32);
  bool h = (threadIdx.x & 32) != 0;
  x = h ? bx : a;
  y = h ? b : ax;
#endif
}

// ---------------- prep: split qkv weights fp32 -> bf16 hi/lo, permuted ----------------
__global__ __launch_bounds__(256) void prep_wq(
    const float* __restrict__ wq1, const float* __restrict__ wq2,
    u16* __restrict__ wh, u16* __restrict__ wl)
{
  int bx = blockIdx.x;                  // 0..4607
  int modal = bx / 2304, rowp = bx % 2304;
  int typ = rowp / 768, hd = rowp % 768;
  const float* W = (modal ? wq2 : wq1) + (size_t)(hd * 3 + typ) * EMB;
  size_t dst = (size_t)bx * EMB;
  int t = threadIdx.x;
  #pragma unroll
  for (int i = 0; i < 3; ++i) {
    int e = t + i * 256;
    float v = W[e];
    u16 h = f2bf(v);
    wh[dst + e] = h;
    wl[dst + e] = f2bf(v - bf2f(h));
  }
}

// prep: w_proj fp32 -> bf16 hi only
__global__ __launch_bounds__(256) void prep_wp(
    const float* __restrict__ wp1, const float* __restrict__ wp2,
    u16* __restrict__ wh)
{
  int bx = blockIdx.x;                  // 0..1535
  int modal = bx / 768, row = bx % 768;
  const float* W = (modal ? wp2 : wp1) + (size_t)row * EMB;
  size_t dst = (size_t)bx * EMB;
  int t = threadIdx.x;
  #pragma unroll
  for (int i = 0; i < 3; ++i) {
    int e = t + i * 256;
    wh[dst + e] = f2bf(W[e]);
  }
}

// ---------------- Kernel 1: LayerNorm (fp32 in) + hi/lo bf16 split ----------------
__global__ __launch_bounds__(256) void k_ln(
    const float* __restrict__ x1, const float* __restrict__ x2,
    const float* __restrict__ g1, const float* __restrict__ b1,
    const float* __restrict__ g2, const float* __restrict__ b2,
    u16* __restrict__ xn_hi, u16* __restrict__ xn_lo)
{
  int row = blockIdx.x;                 // 0..8191, modal-major
  int modal = row >> 12;
  const float* x = modal ? x2 : x1;
  const float* g = modal ? g2 : g1;
  const float* bb = modal ? b2 : b1;
  int r = row & (RPM - 1);
  const float* xr = x + (size_t)r * EMB;
  int t = threadIdx.x;
  float v0 = xr[t], v1 = xr[t + 256], v2 = xr[t + 512];
  float s = v0 + v1 + v2;
  float s2 = v0 * v0 + v1 * v1 + v2 * v2;
  #pragma unroll
  for (int m = 1; m < 64; m <<= 1) { s += __shfl_xor(s, m); s2 += __shfl_xor(s2, m); }
  __shared__ float ls[4], ls2[4];
  int w = t >> 6;
  if ((t & 63) == 0) { ls[w] = s; ls2[w] = s2; }
  __syncthreads();
  s = ls[0] + ls[1] + ls[2] + ls[3];
  s2 = ls2[0] + ls2[1] + ls2[2] + ls2[3];
  float mu = s * (1.0f / EMB);
  float var = s2 * (1.0f / EMB) - mu * mu;
  float rs = rsqrtf(var + 1e-5f);
  size_t base = (size_t)row * EMB;
  float vv[3] = { v0, v1, v2 };
  #pragma unroll
  for (int i = 0; i < 3; ++i) {
    int e = t + i * 256;
    float xn = (vv[i] - mu) * rs * g[e] + bb[e];
    u16 h = f2bf(xn);
    xn_hi[base + e] = h;
    xn_lo[base + e] = f2bf(xn - bf2f(h));
  }
}

// ---------------- Kernel 2: QKV GEMM (pre-split W, global_load_lds staging) ----------
// grid (32 row-tiles, 18 col-tiles, 2 modals), 256 thr. Tile 128x128, BK=32.
// LDS tiles linear [128][32] with 2-bit chunk XOR swizzle: LDS[r][j] = src[r][j^(r&3)].
__global__ __launch_bounds__(256) void k_qkv(
    const u16* __restrict__ xn_hi, const u16* __restrict__ xn_lo,
    const u16* __restrict__ wqh, const u16* __restrict__ wql,
    const float* __restrict__ bq1, const float* __restrict__ bq2,
    u16* __restrict__ q_hi, u16* __restrict__ q_lo,
    u16* __restrict__ k_hi, u16* __restrict__ k_lo,
    u16* __restrict__ vT)
{
  int mt = blockIdx.x, ntile = blockIdx.y, modal = blockIdx.z;
  const float* BQ = modal ? bq2 : bq1;
  int typ = ntile / 6;            // 0=q 1=k 2=v
  int hd0 = (ntile % 6) * 128;

  __shared__ __align__(16) u16 As_hi[128 * 32], Wh[128 * 32], As_lo[128 * 32], Wl[128 * 32];

  int tid = threadIdx.x, lane = tid & 63, w = tid >> 6;
  int wm = (w >> 1) * 64, wn = (w & 1) * 64;
  int lc = lane & 15, lq = lane >> 4;

  int srow = lane >> 2;                          // 0..15: row within 16-row segment
  int schunk = ((lane & 3) ^ (srow & 3)) << 3;   // pre-swizzled source chunk (u16 units)

  floatx4 acc[4][4] = {};
  const u16* aH = xn_hi + (size_t)(modal * RPM + mt * 128) * EMB;
  const u16* aL = xn_lo + (size_t)(modal * RPM + mt * 128) * EMB;
  const u16* wH = wqh + (size_t)(modal * 2304 + typ * 768 + hd0) * EMB;
  const u16* wL = wql + (size_t)(modal * 2304 + typ * 768 + hd0) * EMB;

  for (int k0 = 0; k0 < EMB; k0 += 32) {
    if (typ != 2) {
      #pragma unroll
      for (int c = 0; c < 8; ++c) {
        int seg = w * 8 + c;                     // 0..31
        int tile = seg >> 3, segin = seg & 7;
        size_t off = (size_t)(segin * 16 + srow) * EMB + k0 + schunk;
        const u16* src; u16* dstb;
        if (tile == 0)      { src = aH + off; dstb = As_hi; }
        else if (tile == 1) { src = wH + off; dstb = Wh; }
        else if (tile == 2) { src = aL + off; dstb = As_lo; }
        else                { src = wL + off; dstb = Wl; }
        __builtin_amdgcn_global_load_lds(
            (const __attribute__((address_space(1))) unsigned int*)src,
            (__attribute__((address_space(3))) unsigned int*)(dstb + segin * 512), 16, 0, 0);
      }
    } else {
      #pragma unroll
      for (int c = 0; c < 4; ++c) {
        int seg = w * 4 + c;                     // 0..15
        int tile = seg >> 3, segin = seg & 7;
        size_t off = (size_t)(segin * 16 + srow) * EMB + k0 + schunk;
        const u16* src; u16* dstb;
        if (tile == 0) { src = aH + off; dstb = As_hi; }
        else           { src = wH + off; dstb = Wh; }
        __builtin_amdgcn_global_load_lds(
            (const __attribute__((address_space(1))) unsigned int*)src,
            (__attribute__((address_space(3))) unsigned int*)(dstb + segin * 512), 16, 0, 0);
      }
    }
    __syncthreads();

    shortx8 ah[4], al[4], whf[4], wlf[4];
    int rsw = lc & 3;
    int ca = (lq ^ rsw) << 3;                    // swizzled read chunk (u16 units)
    #pragma unroll
    for (int i = 0; i < 4; ++i) {
      int ra = wm + i * 16 + lc, rw = wn + i * 16 + lc;
      ah[i]  = *(const shortx8*)&As_hi[ra * 32 + ca];
      whf[i] = *(const shortx8*)&Wh[rw * 32 + ca];
      if (typ != 2) {
        al[i]  = *(const shortx8*)&As_lo[ra * 32 + ca];
        wlf[i] = *(const shortx8*)&Wl[rw * 32 + ca];
      }
    }
    #pragma unroll
    for (int i = 0; i < 4; ++i)
      #pragma unroll
      for (int jn = 0; jn < 4; ++jn) {
        acc[i][jn] = __builtin_amdgcn_mfma_f32_16x16x32_bf16(ah[i], whf[jn], acc[i][jn], 0, 0, 0);
        if (typ != 2) {
          acc[i][jn] = __builtin_amdgcn_mfma_f32_16x16x32_bf16(al[i], whf[jn], acc[i][jn], 0, 0, 0);
          acc[i][jn] = __builtin_amdgcn_mfma_f32_16x16x32_bf16(ah[i], wlf[jn], acc[i][jn], 0, 0, 0);
        }
      }
    __syncthreads();
  }

  #pragma unroll
  for (int i = 0; i < 4; ++i) {
    int mrow0 = mt * 128 + wm + i * 16 + lq * 4;
    #pragma unroll
    for (int jn = 0; jn < 4; ++jn) {
      int colp = hd0 + wn + jn * 16 + lc;          // hd index [0,768)
      int h = colp >> 6, d = colp & 63;
      float bias = BQ[colp * 3 + typ];
      #pragma unroll
      for (int r = 0; r < 4; ++r) {
        int mrow = mrow0 + r;
        int b = mrow >> 11, nq = mrow & (SEQ - 1);
        int uu = modal * 24 + b * 12 + h;
        float val = acc[i][jn][r] + bias;
        if (typ == 0) {
          size_t o = ((size_t)uu * SEQ + nq) * HDIM + d;
          u16 hh = f2bf(val); q_hi[o] = hh; q_lo[o] = f2bf(val - bf2f(hh));
        } else if (typ == 1) {
          size_t o = ((size_t)uu * SEQ + nq) * HDIM + d;
          u16 hh = f2bf(val); k_hi[o] = hh; k_lo[o] = f2bf(val - bf2f(hh));
        } else {
          vT[((size_t)uu * HDIM + d) * SEQ + nq] = f2bf(val);
        }
      }
    }
  }
}

// ---------------- Kernel 3: flash attention, swapped-QK^T 32x32, 64 q/wave ----------
// grid (8 q-tiles, 48 units), 256 thr = 4 waves, 64 q-rows/wave (2 groups of 32 sharing
// every K/V LDS fragment). K-chunk 64, dbuf DMA, 1 barrier/iter.
__global__ __launch_bounds__(256, 2) void k_attn(
    const u16* __restrict__ q_hi, const u16* __restrict__ q_lo,
    const u16* __restrict__ k_hi, const u16* __restrict__ k_lo,
    const u16* __restrict__ vT, u16* __restrict__ attn_out)
{
  int qt = blockIdx.x, u = blockIdx.y;
  // [buf][tile]: tile 0 = K_hi [64k][64d], 1 = K_lo, 2 = V^T [64d][64k]; XOR-swizzled
  __shared__ __align__(16) u16 lds[2][3 * KTS];

  int tid = threadIdx.x, lane = tid & 63, w = tid >> 6;
  int col = lane & 31, hi = lane >> 5;
  int swz = (col & 7) << 4;              // read-side swizzle: row&7 == col&7 for all our reads

  // ---- Q fragments in regs: group g: q = base + g*32 + col, d = s*16 + hi*8 + 0..7 ----
  shortx8 qh[2][4], qlo[2][4];
  #pragma unroll
  for (int g = 0; g < 2; ++g) {
    size_t qb = ((size_t)u * SEQ + qt * 256 + w * 64 + g * 32 + col) * HDIM + hi * 8;
    #pragma unroll
    for (int s = 0; s < 4; ++s) {
      qh[g][s]  = *(const shortx8*)(q_hi + qb + s * 16);
      qlo[g][s] = *(const shortx8*)(q_lo + qb + s * 16);
    }
  }

  // ---- staging: 24 x 1KB segments via global_load_lds; source pre-swizzled ----
  int lrow = lane >> 3;                          // 0..7 (row within 8-row segment)
  int lcol = ((lane & 7) ^ lrow) << 3;           // swizzled elem offset within 64
  const u16* kh_src = k_hi + (size_t)u * SEQ * HDIM;
  const u16* kl_src = k_lo + (size_t)u * SEQ * HDIM;
  const u16* v_src  = vT  + (size_t)u * HDIM * SEQ;

  auto stage = [&](int buf, int kc) {
    #pragma unroll
    for (int c = 0; c < 6; ++c) {
      int seg = w * 6 + c;                       // 0..23, wave-uniform
      int tile = seg >> 3, segin = seg & 7;
      u16* dst = &lds[buf][tile * KTS + segin * 512];
      const u16* src;
      if (tile == 0)      src = kh_src + (size_t)(kc + segin * 8 + lrow) * HDIM + lcol;
      else if (tile == 1) src = kl_src + (size_t)(kc + segin * 8 + lrow) * HDIM + lcol;
      else                src = v_src  + (size_t)(segin * 8 + lrow) * SEQ + kc + lcol;
      __builtin_amdgcn_global_load_lds(
          (const __attribute__((address_space(1))) unsigned int*)src,
          (__attribute__((address_space(3))) unsigned int*)dst, 16, 0, 0);
    }
  };

  floatx16 O[2][2] = {};                 // [group][dt]; lane col = d(+32*dt), regs = q(crow)
  float m_r[2] = { -1e30f, -1e30f };
  float lsum[2] = { 0.0f, 0.0f };
  const float Cs = 11.5415603271f;       // 8 * log2(e)
  const float THR = 8.0f;                // defer-max threshold (log2 domain)

  stage(0, 0);
  __syncthreads();

  for (int t = 0; t < SEQ / 64; ++t) {
    int cur = t & 1;
    if (t + 1 < SEQ / 64) stage(cur ^ 1, (t + 1) * 64);

    const char* Kh = (const char*)&lds[cur][0];
    const char* Kl = (const char*)&lds[cur][KTS];
    const char* Vt = (const char*)&lds[cur][2 * KTS];

    // ---- swapped QK^T: S^T[k][q]; lane holds q=col, k = kt*32 + crow(r,hi) ----
    floatx16 S0[2] = {}, S1[2] = {};
    __builtin_amdgcn_s_setprio(1);
    #pragma unroll
    for (int s = 0; s < 4; ++s) {
      int cb = (s * 32 + hi * 16) ^ swz;
      shortx8 kf0 = *(const shortx8*)(Kh + col * 128 + cb);
      shortx8 kc0 = *(const shortx8*)(Kl + col * 128 + cb);
      shortx8 kf1 = *(const shortx8*)(Kh + (32 + col) * 128 + cb);
      shortx8 kc1 = *(const shortx8*)(Kl + (32 + col) * 128 + cb);
      #pragma unroll
      for (int g = 0; g < 2; ++g) {
        S0[g] = __builtin_amdgcn_mfma_f32_32x32x16_bf16(kf0, qh[g][s],  S0[g], 0, 0, 0);
        S1[g] = __builtin_amdgcn_mfma_f32_32x32x16_bf16(kf1, qh[g][s],  S1[g], 0, 0, 0);
        S0[g] = __builtin_amdgcn_mfma_f32_32x32x16_bf16(kf0, qlo[g][s], S0[g], 0, 0, 0);
        S1[g] = __builtin_amdgcn_mfma_f32_32x32x16_bf16(kf1, qlo[g][s], S1[g], 0, 0, 0);
        S0[g] = __builtin_amdgcn_mfma_f32_32x32x16_bf16(kc0, qh[g][s],  S0[g], 0, 0, 0);
        S1[g] = __builtin_amdgcn_mfma_f32_32x32x16_bf16(kc1, qh[g][s],  S1[g], 0, 0, 0);
      }
    }
    __builtin_amdgcn_s_setprio(0);

    // ---- per-group online softmax + in-register pack ----
    shortx8 pf[2][4];
    #pragma unroll
    for (int g = 0; g < 2; ++g) {
      float tm[16];
      #pragma unroll
      for (int r = 0; r < 16; ++r) tm[r] = fmaxf(S0[g][r], S1[g][r]);
      float m0 = fmaxf(fmaxf(tm[0], tm[1]), tm[2]);
      float m1 = fmaxf(fmaxf(tm[3], tm[4]), tm[5]);
      float m2 = fmaxf(fmaxf(tm[6], tm[7]), tm[8]);
      float m3 = fmaxf(fmaxf(tm[9], tm[10]), tm[11]);
      float m4 = fmaxf(fmaxf(tm[12], tm[13]), tm[14]);
      float mx = fmaxf(fmaxf(fmaxf(m0, m1), m2), fmaxf(fmaxf(m3, m4), tm[15]));
      mx *= Cs;
      mx = fmaxf(mx, __shfl_xor(mx, 32));

      if (!__all(mx <= m_r[g] + THR)) {          // rare: rescale O, lsum
        float mn = fmaxf(m_r[g], mx);
        float alpha = __builtin_amdgcn_exp2f(m_r[g] - mn);
        m_r[g] = mn;
        lsum[g] *= alpha;
        #pragma unroll
        for (int r = 0; r < 16; ++r) {           // transpose alpha[q] into O lanes
          int qsrc = (r & 3) + 8 * (r >> 2) + 4 * hi;
          union { float f; int i; } a; a.f = alpha;
          a.i = __builtin_amdgcn_ds_bpermute(qsrc << 2, a.i);
          O[g][0][r] *= a.f; O[g][1][r] *= a.f;
        }
      }

      #pragma unroll
      for (int r = 0; r < 16; ++r) {
        S0[g][r] = __builtin_amdgcn_exp2f(fmaf(Cs, S0[g][r], -m_r[g]));
        S1[g][r] = __builtin_amdgcn_exp2f(fmaf(Cs, S1[g][r], -m_r[g]));
      }
      #pragma unroll
      for (int r = 0; r < 16; ++r) tm[r] = S0[g][r] + S1[g][r];
      #pragma unroll
      for (int st = 8; st >= 1; st >>= 1)
        #pragma unroll
        for (int i = 0; i < st; ++i) tm[i] += tm[i + st];
      lsum[g] += tm[0];

      // pack P -> PV A-frags: 16 cvt_pk + 8 permlane32_swap (T12)
      #pragma unroll
      for (int kt = 0; kt < 2; ++kt)
        #pragma unroll
        for (int h2 = 0; h2 < 2; ++h2) {
          floatx16 Sv = kt ? S1[g] : S0[g];
          int b0 = h2 * 8;
          u32 A = cvtpk_bf16(Sv[b0 + 0], Sv[b0 + 1]);
          u32 B = cvtpk_bf16(Sv[b0 + 2], Sv[b0 + 3]);
          u32 C = cvtpk_bf16(Sv[b0 + 4], Sv[b0 + 5]);
          u32 D = cvtpk_bf16(Sv[b0 + 6], Sv[b0 + 7]);
          u32 w0, w1, w2, w3;
          swap_halves(A, C, w0, w2);
          swap_halves(B, D, w1, w3);
          union { u32 uu[4]; shortx8 ss; } pk_;
          pk_.uu[0] = w0; pk_.uu[1] = w1; pk_.uu[2] = w2; pk_.uu[3] = w3;
          pf[g][kt * 2 + h2] = pk_.ss;
        }
    }

    // ---- PV: O^T += P * V, V frags shared by both groups ----
    __builtin_amdgcn_s_setprio(1);
    #pragma unroll
    for (int ks = 0; ks < 4; ++ks) {
      int cb = (ks * 32 + hi * 16) ^ swz;
      shortx8 v0 = *(const shortx8*)(Vt + col * 128 + cb);
      shortx8 v1 = *(const shortx8*)(Vt + (32 + col) * 128 + cb);
      #pragma unroll
      for (int g = 0; g < 2; ++g) {
        O[g][0] = __builtin_amdgcn_mfma_f32_32x32x16_bf16(pf[g][ks], v0, O[g][0], 0, 0, 0);
        O[g][1] = __builtin_amdgcn_mfma_f32_32x32x16_bf16(pf[g][ks], v1, O[g][1], 0, 0, 0);
      }
    }
    __builtin_amdgcn_s_setprio(0);

    __syncthreads();   // drains vmcnt (next-buf DMA) + lgkm; all waves done reading cur
  }

  // ---- epilogue per group: l = pair-sum, transpose 1/l into O lanes, store ----
  int modal = u / 24, b = (u / 12) & 1, h = u % 12;
  #pragma unroll
  for (int g = 0; g < 2; ++g) {
    float lt = lsum[g] + __shfl_xor(lsum[g], 32);
    float rl = __builtin_amdgcn_rcpf(lt);
    size_t obase = ((size_t)(modal * RPM + b * SEQ + qt * 256 + w * 64 + g * 32)) * EMB
                 + h * 64 + col;
    #pragma unroll
    for (int r = 0; r < 16; ++r) {
      int ql_ = (r & 3) + 8 * (r >> 2) + 4 * hi;   // q-local row of this reg
      union { float f; int i; } a; a.f = rl;
      a.i = __builtin_amdgcn_ds_bpermute(ql_ << 2, a.i);
      size_t ob = obase + (size_t)ql_ * EMB;
      attn_out[ob]      = f2bf(O[g][0][r] * a.f);
      attn_out[ob + 32] = f2bf(O[g][1][r] * a.f);
    }
  }
}

// ---------------- Kernel 4: proj GEMM (pre-split W) + bias + fp32 residual ----------------
__global__ __launch_bounds__(256) void k_proj(
    const u16* __restrict__ ao, const u16* __restrict__ wph,
    const float* __restrict__ x1, const float* __restrict__ x2,
    const float* __restrict__ bp1, const float* __restrict__ bp2,
    float* __restrict__ out)
{
  int mt = blockIdx.x, ntile = blockIdx.y, modal = blockIdx.z;
  const float* BP = modal ? bp2 : bp1;
  const float* x  = modal ? x2 : x1;

  __shared__ u16 As[128 * LDA], Ws[128 * LDA];
  int tid = threadIdx.x, lane = tid & 63, w = tid >> 6;
  int wm = (w >> 1) * 64, wn = (w & 1) * 64;
  int lc = lane & 15, lq = lane >> 4;

  floatx4 acc[4][4] = {};
  size_t arow0 = (size_t)(modal * RPM + mt * 128) * EMB;
  int col0 = ntile * 128;
  size_t wrow0 = (size_t)(modal * 768 + col0) * EMB;

  for (int k0 = 0; k0 < EMB; k0 += 32) {
    #pragma unroll
    for (int i = 0; i < 2; ++i) {
      int c = tid + i * 256;
      int rr = c >> 2, cc = (c & 3) * 8;
      size_t go = (size_t)rr * EMB + k0 + cc;
      *(shortx8*)&As[rr * LDA + cc] = *(const shortx8*)(ao + arow0 + go);
      *(shortx8*)&Ws[rr * LDA + cc] = *(const shortx8*)(wph + wrow0 + go);
    }
    __syncthreads();
    shortx8 af[4], wf[4];
    #pragma unroll
    for (int i = 0; i < 4; ++i) {
      af[i] = *(const shortx8*)&As[(wm + i * 16 + lc) * LDA + lq * 8];
      wf[i] = *(const shortx8*)&Ws[(wn + i * 16 + lc) * LDA + lq * 8];
    }
    #pragma unroll
    for (int i = 0; i < 4; ++i)
      #pragma unroll
      for (int jn = 0; jn < 4; ++jn)
        acc[i][jn] = __builtin_amdgcn_mfma_f32_16x16x32_bf16(af[i], wf[jn], acc[i][jn], 0, 0, 0);
    __syncthreads();
  }

  #pragma unroll
  for (int i = 0; i < 4; ++i) {
    int mrow0 = mt * 128 + wm + i * 16 + lq * 4;
    #pragma unroll
    for (int jn = 0; jn < 4; ++jn) {
      int col = col0 + wn + jn * 16 + lc;
      float bias = BP[col];
      #pragma unroll
      for (int r = 0; r < 4; ++r) {
        int mrow = mrow0 + r;
        float val = acc[i][jn][r] + bias + x[(size_t)mrow * EMB + col];
        out[((size_t)(modal * RPM + mrow)) * EMB + col] = val;
      }
    }
  }
}

extern "C" void kernel_launch(void* const* d_in, const int* in_sizes, int n_in,
                              void* d_out, int out_size, void* d_ws, size_t ws_size,
                              hipStream_t stream) {
  const float* modal1 = (const float*)d_in[0];
  const float* modal2 = (const float*)d_in[1];
  const float* ln1_g  = (const float*)d_in[2];
  const float* ln1_b  = (const float*)d_in[3];
  const float* w_qkv1 = (const float*)d_in[4];
  const float* b_qkv1 = (const float*)d_in[5];
  const float* w_proj1= (const float*)d_in[6];
  const float* b_proj1= (const float*)d_in[7];
  const float* ln2_g  = (const float*)d_in[8];
  const float* ln2_b  = (const float*)d_in[9];
  const float* w_qkv2 = (const float*)d_in[10];
  const float* b_qkv2 = (const float*)d_in[11];
  const float* w_proj2= (const float*)d_in[12];
  const float* b_proj2= (const float*)d_in[13];
  float* out = (float*)d_out;

  const size_t BUFE = (size_t)NROW * EMB;       // 6291456 elems
  const size_t WQE  = (size_t)2 * 2304 * EMB;   // 3538944 elems
  u16* xn_hi = (u16*)d_ws;
  u16* xn_lo = xn_hi + BUFE;
  u16* q_hi  = xn_lo + BUFE;
  u16* q_lo  = q_hi + BUFE;
  u16* k_hi  = q_lo + BUFE;
  u16* k_lo  = k_hi + BUFE;
  u16* vT    = k_lo + BUFE;
  u16* wq_h  = vT + BUFE;
  u16* wq_l  = wq_h + WQE;
  u16* attn  = xn_hi;   // xn dead after k_qkv
  u16* wp_h  = q_lo;    // q_lo dead after k_attn (w_proj needs 1.18M < 6.29M elems)

  prep_wq<<<4608, 256, 0, stream>>>(w_qkv1, w_qkv2, wq_h, wq_l);
  k_ln<<<NROW, 256, 0, stream>>>(modal1, modal2, ln1_g, ln1_b, ln2_g, ln2_b, xn_hi, xn_lo);
  dim3 g2(32, 18, 2);
  k_qkv<<<g2, 256, 0, stream>>>(xn_hi, xn_lo, wq_h, wq_l, b_qkv1, b_qkv2,
                                q_hi, q_lo, k_hi, k_lo, vT);
  dim3 g3(8, 48);
  k_attn<<<g3, 256, 0, stream>>>(q_hi, q_lo, k_hi, k_lo, vT, attn);
  prep_wp<<<1536, 256, 0, stream>>>(w_proj1, w_proj2, wp_h);
  dim3 g4(32, 6, 2);
  k_proj<<<g4, 256, 0, stream>>>(attn, wp_h, modal1, modal2, b_proj1, b_proj2, out);
}

// Round 3
// 355.472 us; speedup vs baseline: 1.2496x; 1.2496x over previous
//
#include <hip/hip_runtime.h>
#include <hip/hip_bf16.h>

// r5: 357us; k_attn 127us (latency-bound: no pipe >45%, FETCH 161MB vs 61MB unique = L2 thrash).
// r6: FAILED: 64q/wave spilled (VGPR capped 128, WRITE +10MB scratch) + grid 384 = 1.5/CU -> 223us.
// r7: k_attn = r5 body + XCD-aware block remap (unit's 16 blocks -> same XCD; K/V L2-resident).
//     k_proj: global_load_lds staging, 64x128 tile (768 blocks = 3/CU). k_qkv unchanged (r6).

typedef unsigned short u16;
typedef unsigned int   u32;
typedef __attribute__((ext_vector_type(4)))  float floatx4;
typedef __attribute__((ext_vector_type(16))) float floatx16;
typedef __attribute__((ext_vector_type(8)))  short shortx8;
typedef __attribute__((ext_vector_type(2)))  unsigned int uintx2;

#define EMB   768
#define SEQ   2048
#define NHEAD 12
#define HDIM  64
#define RPM   4096   // rows per modal (B*N)
#define NROW  8192   // total rows (2 modals)
#define NUNIT 48     // modal*B*H units
#define KTS   4096   // attn LDS tile elems (64*64)

__device__ __forceinline__ float bf2f(u16 h) {
  union { u32 u; float f; } v; v.u = ((u32)h) << 16; return v.f;
}
__device__ __forceinline__ u16 f2bf(float f) {            // RNE
  union { float f; u32 u; } v; v.f = f;
  u32 r = v.u + 0x7fffu + ((v.u >> 16) & 1u);
  return (u16)(r >> 16);
}
__device__ __forceinline__ u32 cvtpk_bf16(float a, float b) {  // lo16=bf16(a), hi16=bf16(b)
  u32 r;
  asm("v_cvt_pk_bf16_f32 %0, %1, %2" : "=v"(r) : "v"(a), "v"(b));
  return r;
}
// x = {a.lo32lanes, b.lo32lanes}, y = {a.hi32lanes, b.hi32lanes}
__device__ __forceinline__ void swap_halves(u32 a, u32 b, u32& x, u32& y) {
#if __has_builtin(__builtin_amdgcn_permlane32_swap)
  uintx2 r = __builtin_amdgcn_permlane32_swap(a, b, false, false);
  x = r.x; y = r.y;
#else
  u32 ax = (u32)__shfl_xor((int)a, 32);
  u32 bx = (u32)__shfl_xor((int)b, 32);
  bool h = (threadIdx.x & 32) != 0;
  x = h ? bx : a;
  y = h ? b : ax;
#endif
}

// ---------------- prep: split qkv weights fp32 -> bf16 hi/lo, permuted ----------------
__global__ __launch_bounds__(256) void prep_wq(
    const float* __restrict__ wq1, const float* __restrict__ wq2,
    u16* __restrict__ wh, u16* __restrict__ wl)
{
  int bx = blockIdx.x;                  // 0..4607
  int modal = bx / 2304, rowp = bx % 2304;
  int typ = rowp / 768, hd = rowp % 768;
  const float* W = (modal ? wq2 : wq1) + (size_t)(hd * 3 + typ) * EMB;
  size_t dst = (size_t)bx * EMB;
  int t = threadIdx.x;
  #pragma unroll
  for (int i = 0; i < 3; ++i) {
    int e = t + i * 256;
    float v = W[e];
    u16 h = f2bf(v);
    wh[dst + e] = h;
    wl[dst + e] = f2bf(v - bf2f(h));
  }
}

// prep: w_proj fp32 -> bf16 hi only
__global__ __launch_bounds__(256) void prep_wp(
    const float* __restrict__ wp1, const float* __restrict__ wp2,
    u16* __restrict__ wh)
{
  int bx = blockIdx.x;                  // 0..1535
  int modal = bx / 768, row = bx % 768;
  const float* W = (modal ? wp2 : wp1) + (size_t)row * EMB;
  size_t dst = (size_t)bx * EMB;
  int t = threadIdx.x;
  #pragma unroll
  for (int i = 0; i < 3; ++i) {
    int e = t + i * 256;
    wh[dst + e] = f2bf(W[e]);
  }
}

// ---------------- Kernel 1: LayerNorm (fp32 in) + hi/lo bf16 split ----------------
__global__ __launch_bounds__(256) void k_ln(
    const float* __restrict__ x1, const float* __restrict__ x2,
    const float* __restrict__ g1, const float* __restrict__ b1,
    const float* __restrict__ g2, const float* __restrict__ b2,
    u16* __restrict__ xn_hi, u16* __restrict__ xn_lo)
{
  int row = blockIdx.x;                 // 0..8191, modal-major
  int modal = row >> 12;
  const float* x = modal ? x2 : x1;
  const float* g = modal ? g2 : g1;
  const float* bb = modal ? b2 : b1;
  int r = row & (RPM - 1);
  const float* xr = x + (size_t)r * EMB;
  int t = threadIdx.x;
  float v0 = xr[t], v1 = xr[t + 256], v2 = xr[t + 512];
  float s = v0 + v1 + v2;
  float s2 = v0 * v0 + v1 * v1 + v2 * v2;
  #pragma unroll
  for (int m = 1; m < 64; m <<= 1) { s += __shfl_xor(s, m); s2 += __shfl_xor(s2, m); }
  __shared__ float ls[4], ls2[4];
  int w = t >> 6;
  if ((t & 63) == 0) { ls[w] = s; ls2[w] = s2; }
  __syncthreads();
  s = ls[0] + ls[1] + ls[2] + ls[3];
  s2 = ls2[0] + ls2[1] + ls2[2] + ls2[3];
  float mu = s * (1.0f / EMB);
  float var = s2 * (1.0f / EMB) - mu * mu;
  float rs = rsqrtf(var + 1e-5f);
  size_t base = (size_t)row * EMB;
  float vv[3] = { v0, v1, v2 };
  #pragma unroll
  for (int i = 0; i < 3; ++i) {
    int e = t + i * 256;
    float xn = (vv[i] - mu) * rs * g[e] + bb[e];
    u16 h = f2bf(xn);
    xn_hi[base + e] = h;
    xn_lo[base + e] = f2bf(xn - bf2f(h));
  }
}

// ---------------- Kernel 2: QKV GEMM (pre-split W, global_load_lds staging) ----------
// grid (32 row-tiles, 18 col-tiles, 2 modals), 256 thr. Tile 128x128, BK=32.
// LDS tiles linear [128][32] with 2-bit chunk XOR swizzle: LDS[r][j] = src[r][j^(r&3)].
__global__ __launch_bounds__(256) void k_qkv(
    const u16* __restrict__ xn_hi, const u16* __restrict__ xn_lo,
    const u16* __restrict__ wqh, const u16* __restrict__ wql,
    const float* __restrict__ bq1, const float* __restrict__ bq2,
    u16* __restrict__ q_hi, u16* __restrict__ q_lo,
    u16* __restrict__ k_hi, u16* __restrict__ k_lo,
    u16* __restrict__ vT)
{
  int mt = blockIdx.x, ntile = blockIdx.y, modal = blockIdx.z;
  const float* BQ = modal ? bq2 : bq1;
  int typ = ntile / 6;            // 0=q 1=k 2=v
  int hd0 = (ntile % 6) * 128;

  __shared__ __align__(16) u16 As_hi[128 * 32], Wh[128 * 32], As_lo[128 * 32], Wl[128 * 32];

  int tid = threadIdx.x, lane = tid & 63, w = tid >> 6;
  int wm = (w >> 1) * 64, wn = (w & 1) * 64;
  int lc = lane & 15, lq = lane >> 4;

  int srow = lane >> 2;                          // 0..15: row within 16-row segment
  int schunk = ((lane & 3) ^ (srow & 3)) << 3;   // pre-swizzled source chunk (u16 units)

  floatx4 acc[4][4] = {};
  const u16* aH = xn_hi + (size_t)(modal * RPM + mt * 128) * EMB;
  const u16* aL = xn_lo + (size_t)(modal * RPM + mt * 128) * EMB;
  const u16* wH = wqh + (size_t)(modal * 2304 + typ * 768 + hd0) * EMB;
  const u16* wL = wql + (size_t)(modal * 2304 + typ * 768 + hd0) * EMB;

  for (int k0 = 0; k0 < EMB; k0 += 32) {
    if (typ != 2) {
      #pragma unroll
      for (int c = 0; c < 8; ++c) {
        int seg = w * 8 + c;                     // 0..31
        int tile = seg >> 3, segin = seg & 7;
        size_t off = (size_t)(segin * 16 + srow) * EMB + k0 + schunk;
        const u16* src; u16* dstb;
        if (tile == 0)      { src = aH + off; dstb = As_hi; }
        else if (tile == 1) { src = wH + off; dstb = Wh; }
        else if (tile == 2) { src = aL + off; dstb = As_lo; }
        else                { src = wL + off; dstb = Wl; }
        __builtin_amdgcn_global_load_lds(
            (const __attribute__((address_space(1))) unsigned int*)src,
            (__attribute__((address_space(3))) unsigned int*)(dstb + segin * 512), 16, 0, 0);
      }
    } else {
      #pragma unroll
      for (int c = 0; c < 4; ++c) {
        int seg = w * 4 + c;                     // 0..15
        int tile = seg >> 3, segin = seg & 7;
        size_t off = (size_t)(segin * 16 + srow) * EMB + k0 + schunk;
        const u16* src; u16* dstb;
        if (tile == 0) { src = aH + off; dstb = As_hi; }
        else           { src = wH + off; dstb = Wh; }
        __builtin_amdgcn_global_load_lds(
            (const __attribute__((address_space(1))) unsigned int*)src,
            (__attribute__((address_space(3))) unsigned int*)(dstb + segin * 512), 16, 0, 0);
      }
    }
    __syncthreads();

    shortx8 ah[4], al[4], whf[4], wlf[4];
    int rsw = lc & 3;
    int ca = (lq ^ rsw) << 3;                    // swizzled read chunk (u16 units)
    #pragma unroll
    for (int i = 0; i < 4; ++i) {
      int ra = wm + i * 16 + lc, rw = wn + i * 16 + lc;
      ah[i]  = *(const shortx8*)&As_hi[ra * 32 + ca];
      whf[i] = *(const shortx8*)&Wh[rw * 32 + ca];
      if (typ != 2) {
        al[i]  = *(const shortx8*)&As_lo[ra * 32 + ca];
        wlf[i] = *(const shortx8*)&Wl[rw * 32 + ca];
      }
    }
    #pragma unroll
    for (int i = 0; i < 4; ++i)
      #pragma unroll
      for (int jn = 0; jn < 4; ++jn) {
        acc[i][jn] = __builtin_amdgcn_mfma_f32_16x16x32_bf16(ah[i], whf[jn], acc[i][jn], 0, 0, 0);
        if (typ != 2) {
          acc[i][jn] = __builtin_amdgcn_mfma_f32_16x16x32_bf16(al[i], whf[jn], acc[i][jn], 0, 0, 0);
          acc[i][jn] = __builtin_amdgcn_mfma_f32_16x16x32_bf16(ah[i], wlf[jn], acc[i][jn], 0, 0, 0);
        }
      }
    __syncthreads();
  }

  #pragma unroll
  for (int i = 0; i < 4; ++i) {
    int mrow0 = mt * 128 + wm + i * 16 + lq * 4;
    #pragma unroll
    for (int jn = 0; jn < 4; ++jn) {
      int colp = hd0 + wn + jn * 16 + lc;          // hd index [0,768)
      int h = colp >> 6, d = colp & 63;
      float bias = BQ[colp * 3 + typ];
      #pragma unroll
      for (int r = 0; r < 4; ++r) {
        int mrow = mrow0 + r;
        int b = mrow >> 11, nq = mrow & (SEQ - 1);
        int uu = modal * 24 + b * 12 + h;
        float val = acc[i][jn][r] + bias;
        if (typ == 0) {
          size_t o = ((size_t)uu * SEQ + nq) * HDIM + d;
          u16 hh = f2bf(val); q_hi[o] = hh; q_lo[o] = f2bf(val - bf2f(hh));
        } else if (typ == 1) {
          size_t o = ((size_t)uu * SEQ + nq) * HDIM + d;
          u16 hh = f2bf(val); k_hi[o] = hh; k_lo[o] = f2bf(val - bf2f(hh));
        } else {
          vT[((size_t)uu * HDIM + d) * SEQ + nq] = f2bf(val);
        }
      }
    }
  }
}

// ---------------- Kernel 3: flash attention, swapped-QK^T 32x32, 32 q/wave ----------
// grid (16,48) remapped XCD-aware: all 16 q-tile blocks of a unit land on one XCD
// so the unit's 768KB K/V set stays L2-resident. Body = r5 (verified 127us).
__global__ __launch_bounds__(256, 3) void k_attn(
    const u16* __restrict__ q_hi, const u16* __restrict__ q_lo,
    const u16* __restrict__ k_hi, const u16* __restrict__ k_lo,
    const u16* __restrict__ vT, u16* __restrict__ attn_out)
{
  // XCD-aware remap: linear id (x fastest), xcd = id&7 under round-robin dispatch.
  int id = blockIdx.x + (blockIdx.y << 4);       // 0..767
  int xcd = id & 7, j = id >> 3;                 // j: 0..95
  int u = xcd * 6 + (j >> 4);                    // 6 units per XCD
  int qt = j & 15;

  // [buf][tile]: tile 0 = K_hi [64k][64d], 1 = K_lo, 2 = V^T [64d][64k]; XOR-swizzled
  __shared__ __align__(16) u16 lds[2][3 * KTS];

  int tid = threadIdx.x, lane = tid & 63, w = tid >> 6;
  int col = lane & 31, hi = lane >> 5;
  int swz = (col & 7) << 4;              // read-side swizzle: row&7 == col&7 for all our reads

  // ---- Q fragments in regs: lane holds q = base+col, d = s*16 + hi*8 + 0..7 ----
  shortx8 qh[4], qlo[4];
  {
    size_t qb = ((size_t)u * SEQ + qt * 128 + w * 32 + col) * HDIM + hi * 8;
    #pragma unroll
    for (int s = 0; s < 4; ++s) {
      qh[s]  = *(const shortx8*)(q_hi + qb + s * 16);
      qlo[s] = *(const shortx8*)(q_lo + qb + s * 16);
    }
  }

  // ---- staging: 24 x 1KB segments via global_load_lds; source pre-swizzled ----
  int lrow = lane >> 3;                          // 0..7 (row within 8-row segment)
  int lcol = ((lane & 7) ^ lrow) << 3;           // swizzled elem offset within 64
  const u16* kh_src = k_hi + (size_t)u * SEQ * HDIM;
  const u16* kl_src = k_lo + (size_t)u * SEQ * HDIM;
  const u16* v_src  = vT  + (size_t)u * HDIM * SEQ;

  auto stage = [&](int buf, int kc) {
    #pragma unroll
    for (int c = 0; c < 6; ++c) {
      int seg = w * 6 + c;                       // 0..23, wave-uniform
      int tile = seg >> 3, segin = seg & 7;
      u16* dst = &lds[buf][tile * KTS + segin * 512];
      const u16* src;
      if (tile == 0)      src = kh_src + (size_t)(kc + segin * 8 + lrow) * HDIM + lcol;
      else if (tile == 1) src = kl_src + (size_t)(kc + segin * 8 + lrow) * HDIM + lcol;
      else                src = v_src  + (size_t)(segin * 8 + lrow) * SEQ + kc + lcol;
      __builtin_amdgcn_global_load_lds(
          (const __attribute__((address_space(1))) unsigned int*)src,
          (__attribute__((address_space(3))) unsigned int*)dst, 16, 0, 0);
    }
  };

  floatx16 O0 = {}, O1 = {};                     // O^T: lane col = d(+32*dt), regs = q (crow)
  float m_r = -1e30f, lsum = 0.0f;               // per-lane: q = col (log2-scaled domain)
  const float Cs = 11.5415603271f;  // 8 * log2(e)
  const float THR = 8.0f;                        // defer-max threshold (log2 domain)

  stage(0, 0);
  __syncthreads();

  for (int t = 0; t < SEQ / 64; ++t) {
    int cur = t & 1;
    if (t + 1 < SEQ / 64) stage(cur ^ 1, (t + 1) * 64);

    const char* Kh = (const char*)&lds[cur][0];
    const char* Kl = (const char*)&lds[cur][KTS];
    const char* Vt = (const char*)&lds[cur][2 * KTS];

    // ---- swapped QK^T: S^T[k][q]; lane holds q=col, k = kt*32 + crow(r,hi) ----
    floatx16 S0 = {}, S1 = {};
    __builtin_amdgcn_s_setprio(1);
    #pragma unroll
    for (int s = 0; s < 4; ++s) {
      int cb = (s * 32 + hi * 16) ^ swz;
      shortx8 kf0 = *(const shortx8*)(Kh + col * 128 + cb);
      shortx8 kl0 = *(const shortx8*)(Kl + col * 128 + cb);
      shortx8 kf1 = *(const shortx8*)(Kh + (32 + col) * 128 + cb);
      shortx8 kl1 = *(const shortx8*)(Kl + (32 + col) * 128 + cb);
      S0 = __builtin_amdgcn_mfma_f32_32x32x16_bf16(kf0, qh[s],  S0, 0, 0, 0);
      S1 = __builtin_amdgcn_mfma_f32_32x32x16_bf16(kf1, qh[s],  S1, 0, 0, 0);
      S0 = __builtin_amdgcn_mfma_f32_32x32x16_bf16(kf0, qlo[s], S0, 0, 0, 0);
      S1 = __builtin_amdgcn_mfma_f32_32x32x16_bf16(kf1, qlo[s], S1, 0, 0, 0);
      S0 = __builtin_amdgcn_mfma_f32_32x32x16_bf16(kl0, qh[s],  S0, 0, 0, 0);
      S1 = __builtin_amdgcn_mfma_f32_32x32x16_bf16(kl1, qh[s],  S1, 0, 0, 0);
    }
    __builtin_amdgcn_s_setprio(0);

    // ---- lane-local chunk max (tree), pair-reduce across lane^32 ----
    float tm[16];
    #pragma unroll
    for (int r = 0; r < 16; ++r) tm[r] = fmaxf(S0[r], S1[r]);
    #pragma unroll
    for (int st = 8; st >= 1; st >>= 1)
      #pragma unroll
      for (int i = 0; i < st; ++i) tm[i] = fmaxf(tm[i], tm[i + st]);
    float mx = tm[0] * Cs;
    mx = fmaxf(mx, __shfl_xor(mx, 32));

    // ---- defer-max rescale (T13): only when chunk max grows past m+THR ----
    if (!__all(mx <= m_r + THR)) {
      float mn = fmaxf(m_r, mx);
      float alpha = __builtin_amdgcn_exp2f(m_r - mn);
      m_r = mn;
      lsum *= alpha;
      #pragma unroll
      for (int r = 0; r < 16; ++r) {               // transpose alpha[q] into O lanes
        int qsrc = (r & 3) + 8 * (r >> 2) + 4 * hi;
        union { float f; int i; } a; a.f = alpha;
        a.i = __builtin_amdgcn_ds_bpermute(qsrc << 2, a.i);
        O0[r] *= a.f; O1[r] *= a.f;
      }
    }

    // ---- P = exp2(Cs*S - m) in place; lane-local partial row-sum ----
    #pragma unroll
    for (int r = 0; r < 16; ++r) {
      S0[r] = __builtin_amdgcn_exp2f(fmaf(Cs, S0[r], -m_r));
      S1[r] = __builtin_amdgcn_exp2f(fmaf(Cs, S1[r], -m_r));
    }
    #pragma unroll
    for (int r = 0; r < 16; ++r) tm[r] = S0[r] + S1[r];
    #pragma unroll
    for (int st = 8; st >= 1; st >>= 1)
      #pragma unroll
      for (int i = 0; i < st; ++i) tm[i] += tm[i + st];
    lsum += tm[0];

    // ---- pack P -> PV A-frags: 16 cvt_pk + 8 permlane32_swap (T12) ----
    shortx8 pf[4];
    #pragma unroll
    for (int kt = 0; kt < 2; ++kt)
      #pragma unroll
      for (int h2 = 0; h2 < 2; ++h2) {
        floatx16 Sv = kt ? S1 : S0;
        int b0 = h2 * 8;
        u32 A = cvtpk_bf16(Sv[b0 + 0], Sv[b0 + 1]);
        u32 B = cvtpk_bf16(Sv[b0 + 2], Sv[b0 + 3]);
        u32 C = cvtpk_bf16(Sv[b0 + 4], Sv[b0 + 5]);
        u32 D = cvtpk_bf16(Sv[b0 + 6], Sv[b0 + 7]);
        u32 w0, w1, w2, w3;
        swap_halves(A, C, w0, w2);
        swap_halves(B, D, w1, w3);
        union { u32 uu[4]; shortx8 ss; } pk_;
        pk_.uu[0] = w0; pk_.uu[1] = w1; pk_.uu[2] = w2; pk_.uu[3] = w3;
        pf[kt * 2 + h2] = pk_.ss;
      }

    // ---- PV: O^T += P * V  (A = P frags, B = V^T rows=d from LDS) ----
    __builtin_amdgcn_s_setprio(1);
    #pragma unroll
    for (int ks = 0; ks < 4; ++ks) {
      int cb = (ks * 32 + hi * 16) ^ swz;
      shortx8 v0 = *(const shortx8*)(Vt + col * 128 + cb);
      shortx8 v1 = *(const shortx8*)(Vt + (32 + col) * 128 + cb);
      O0 = __builtin_amdgcn_mfma_f32_32x32x16_bf16(pf[ks], v0, O0, 0, 0, 0);
      O1 = __builtin_amdgcn_mfma_f32_32x32x16_bf16(pf[ks], v1, O1, 0, 0, 0);
    }
    __builtin_amdgcn_s_setprio(0);

    __syncthreads();   // drains vmcnt (next-buf DMA) + lgkm; all waves done reading cur
  }

  // ---- epilogue: l = pair-sum, transpose 1/l into O lanes, store ----
  float lt = lsum + __shfl_xor(lsum, 32);
  float rl = __builtin_amdgcn_rcpf(lt);
  int modal = u / 24, b = (u / 12) & 1, h = u % 12;
  size_t obase = ((size_t)(modal * RPM + b * SEQ + qt * 128 + w * 32)) * EMB + h * 64 + col;
  #pragma unroll
  for (int r = 0; r < 16; ++r) {
    int ql_ = (r & 3) + 8 * (r >> 2) + 4 * hi;     // q-local row of this reg
    union { float f; int i; } a; a.f = rl;
    a.i = __builtin_amdgcn_ds_bpermute(ql_ << 2, a.i);
    size_t ob = obase + (size_t)ql_ * EMB;
    attn_out[ob]      = f2bf(O0[r] * a.f);
    attn_out[ob + 32] = f2bf(O1[r] * a.f);
  }
}

// ---------------- Kernel 4: proj GEMM + bias + fp32 residual (global_load_lds) -------
// grid (64 row-tiles, 6 col-tiles, 2 modals), 256 thr. Tile 64x128, BK=32.
__global__ __launch_bounds__(256) void k_proj(
    const u16* __restrict__ ao, const u16* __restrict__ wph,
    const float* __restrict__ x1, const float* __restrict__ x2,
    const float* __restrict__ bp1, const float* __restrict__ bp2,
    float* __restrict__ out)
{
  int mt = blockIdx.x, ntile = blockIdx.y, modal = blockIdx.z;
  const float* BP = modal ? bp2 : bp1;
  const float* x  = modal ? x2 : x1;

  __shared__ __align__(16) u16 As[64 * 32], Ws[128 * 32];
  int tid = threadIdx.x, lane = tid & 63, w = tid >> 6;
  int wm = (w >> 1) * 32, wn = (w & 1) * 64;
  int lc = lane & 15, lq = lane >> 4;

  int srow = lane >> 2;                          // 0..15
  int schunk = ((lane & 3) ^ (srow & 3)) << 3;   // pre-swizzled source chunk

  floatx4 acc[2][4] = {};
  const u16* aP = ao  + (size_t)(modal * RPM + mt * 64) * EMB;
  const u16* wP = wph + (size_t)(modal * 768 + ntile * 128) * EMB;

  for (int k0 = 0; k0 < EMB; k0 += 32) {
    #pragma unroll
    for (int c = 0; c < 3; ++c) {
      int seg = w * 3 + c;                       // 0..11: 0..3 = As, 4..11 = Ws
      const u16* src; u16* dst;
      if (seg < 4) {
        src = aP + (size_t)(seg * 16 + srow) * EMB + k0 + schunk;
        dst = As + seg * 512;
      } else {
        int s2 = seg - 4;
        src = wP + (size_t)(s2 * 16 + srow) * EMB + k0 + schunk;
        dst = Ws + s2 * 512;
      }
      __builtin_amdgcn_global_load_lds(
          (const __attribute__((address_space(1))) unsigned int*)src,
          (__attribute__((address_space(3))) unsigned int*)dst, 16, 0, 0);
    }
    __syncthreads();

    int ca = (lq ^ (lc & 3)) << 3;
    shortx8 af[2], wf[4];
    #pragma unroll
    for (int i = 0; i < 2; ++i) af[i] = *(const shortx8*)&As[(wm + i * 16 + lc) * 32 + ca];
    #pragma unroll
    for (int i = 0; i < 4; ++i) wf[i] = *(const shortx8*)&Ws[(wn + i * 16 + lc) * 32 + ca];
    #pragma unroll
    for (int i = 0; i < 2; ++i)
      #pragma unroll
      for (int jn = 0; jn < 4; ++jn)
        acc[i][jn] = __builtin_amdgcn_mfma_f32_16x16x32_bf16(af[i], wf[jn], acc[i][jn], 0, 0, 0);
    __syncthreads();
  }

  #pragma unroll
  for (int i = 0; i < 2; ++i) {
    int mrow0 = mt * 64 + wm + i * 16 + lq * 4;
    #pragma unroll
    for (int jn = 0; jn < 4; ++jn) {
      int col = ntile * 128 + wn + jn * 16 + lc;
      float bias = BP[col];
      #pragma unroll
      for (int r = 0; r < 4; ++r) {
        int mrow = mrow0 + r;
        float val = acc[i][jn][r] + bias + x[(size_t)mrow * EMB + col];
        out[((size_t)(modal * RPM + mrow)) * EMB + col] = val;
      }
    }
  }
}

extern "C" void kernel_launch(void* const* d_in, const int* in_sizes, int n_in,
                              void* d_out, int out_size, void* d_ws, size_t ws_size,
                              hipStream_t stream) {
  const float* modal1 = (const float*)d_in[0];
  const float* modal2 = (const float*)d_in[1];
  const float* ln1_g  = (const float*)d_in[2];
  const float* ln1_b  = (const float*)d_in[3];
  const float* w_qkv1 = (const float*)d_in[4];
  const float* b_qkv1 = (const float*)d_in[5];
  const float* w_proj1= (const float*)d_in[6];
  const float* b_proj1= (const float*)d_in[7];
  const float* ln2_g  = (const float*)d_in[8];
  const float* ln2_b  = (const float*)d_in[9];
  const float* w_qkv2 = (const float*)d_in[10];
  const float* b_qkv2 = (const float*)d_in[11];
  const float* w_proj2= (const float*)d_in[12];
  const float* b_proj2= (const float*)d_in[13];
  float* out = (float*)d_out;

  const size_t BUFE = (size_t)NROW * EMB;       // 6291456 elems
  const size_t WQE  = (size_t)2 * 2304 * EMB;   // 3538944 elems
  u16* xn_hi = (u16*)d_ws;
  u16* xn_lo = xn_hi + BUFE;
  u16* q_hi  = xn_lo + BUFE;
  u16* q_lo  = q_hi + BUFE;
  u16* k_hi  = q_lo + BUFE;
  u16* k_lo  = k_hi + BUFE;
  u16* vT    = k_lo + BUFE;
  u16* wq_h  = vT + BUFE;
  u16* wq_l  = wq_h + WQE;
  u16* attn  = xn_hi;   // xn dead after k_qkv
  u16* wp_h  = q_lo;    // q_lo dead after k_attn (w_proj needs 1.18M < 6.29M elems)

  prep_wq<<<4608, 256, 0, stream>>>(w_qkv1, w_qkv2, wq_h, wq_l);
  k_ln<<<NROW, 256, 0, stream>>>(modal1, modal2, ln1_g, ln1_b, ln2_g, ln2_b, xn_hi, xn_lo);
  dim3 g2(32, 18, 2);
  k_qkv<<<g2, 256, 0, stream>>>(xn_hi, xn_lo, wq_h, wq_l, b_qkv1, b_qkv2,
                                q_hi, q_lo, k_hi, k_lo, vT);
  dim3 g3(16, 48);
  k_attn<<<g3, 256, 0, stream>>>(q_hi, q_lo, k_hi, k_lo, vT, attn);
  prep_wp<<<1536, 256, 0, stream>>>(w_proj1, w_proj2, wp_h);
  dim3 g4(64, 6, 2);
  k_proj<<<g4, 256, 0, stream>>>(attn, wp_h, modal1, modal2, b_proj1, b_proj2, out);
}